// Round 6
// baseline (1029.508 us; speedup 1.0000x reference)
//
#include <hip/hip_runtime.h>
#include <hip/hip_bf16.h>

#define N_NODES 100000
#define N_EDGES 3200000
#define E_TILES  (N_EDGES / 16)  // 16 edges per wave-iteration
#define N_GROUPS (N_NODES / 8)
#define NXCD 8
#define NUP_STRIDE (N_NODES * 32)

// weight sub-offsets in g_W (fp32 copies)
#define EW1_O 0
#define EB1_O 2816
#define EW2_O 2848
#define EB2_O 3872
#define NW1_O 3904
#define NB1_O 6176
#define NW2_O 6208
#define NB2_O 6240

typedef unsigned short ushort_t;
typedef __attribute__((ext_vector_type(8))) short bf16x8;
typedef __attribute__((ext_vector_type(4))) float f32x4;

// Device-global state, rebuilt from inputs on EVERY call.
__device__ float    g_nup[NXCD * NUP_STRIDE];  // 8 XCD-private scatter copies
__device__ float    g_W[6244];                 // fp32 weights
__device__ ushort_t g_Wbf1[2][96 * 32];        // W1 split planes (hi,lo), K 88->96 pad
__device__ ushort_t g_Wbf2[2][32 * 32];        // W2 split planes (hi,lo)
// packed split-bf16 feature tables; word = hi | (lo<<16).  ALL gl16 sources must
// be 16B-aligned (round-5 NaN root cause) -> padded/shifted layouts:
__device__ unsigned g_nI[N_NODES * 40];        // node feats, rows padded 39->40
__device__ unsigned g_nJ[N_NODES * 40];        // node feats shifted by 3 (dst window)
__device__ unsigned g_eF[N_EDGES * 12];        // edge feats {EF1..8, EF0, EF9, 0,0}
__device__ int      g_flags[2];                // [0]: bf16 inputs; [1]: int64 idx

__device__ __forceinline__ float bf2f(unsigned short u) {
    union { unsigned int i; float f; } c; c.i = ((unsigned int)u) << 16; return c.f;
}
__device__ __forceinline__ float ubf2f(unsigned u) {
    union { unsigned int i; float f; } c; c.i = u << 16; return c.f;
}
__device__ __forceinline__ unsigned f2bf_u(float f) {
    union { float f; unsigned u; } c; c.f = f;
    return (c.u + 0x7fffu + ((c.u >> 16) & 1u)) >> 16;
}
__device__ __forceinline__ unsigned packsplit(float x) {
    unsigned h = f2bf_u(x);
    unsigned l = f2bf_u(x - ubf2f(h));
    return (h & 0xffffu) | (l << 16);
}
__device__ __forceinline__ float rd_any(const void* p, int i, bool bf) {
    if (bf) return bf2f(((const unsigned short*)p)[i]);
    return ((const float*)p)[i];
}
__device__ __forceinline__ float fast_tanh(float x) {
    float ax = fabsf(x);
    float e  = __expf(ax * 2.0f);
    float t  = 1.0f - 2.0f / (e + 1.0f);
    return copysignf(t, x);
}

// async global->LDS, FULL-EXEC only (validated semantics: uniform LDS base,
// per-lane global src, lane l writes at base + l*size). 16B src alignment req'd.
__device__ __forceinline__ void gl16(const unsigned* g, unsigned* l) {
    __builtin_amdgcn_global_load_lds((const __attribute__((address_space(1))) void*)g,
                                     (__attribute__((address_space(3))) void*)l, 16, 0, 0);
}
__device__ __forceinline__ void gl4(const unsigned* g, unsigned* l) {
    __builtin_amdgcn_global_load_lds((const __attribute__((address_space(1))) void*)g,
                                     (__attribute__((address_space(3))) void*)l, 4, 0, 0);
}

__global__ void detect_kernel(const unsigned short* __restrict__ ew1_raw,
                              const int* __restrict__ ei32) {
    __shared__ int s_ok, s_nzodd;
    if (threadIdx.x == 0) { s_ok = 1; s_nzodd = 0; }
    __syncthreads();
    bool ok = true;
    for (int i = threadIdx.x; i < 2816; i += 256) {
        float v = bf2f(ew1_raw[i]);
        if (!(fabsf(v) <= 0.25f)) ok = false;
    }
    if (!ok) atomicAnd(&s_ok, 0);
    int cnt = 0;
    for (int i = threadIdx.x; i < 2048; i += 256)
        if (ei32[2 * i + 1] != 0) cnt++;
    if (cnt) atomicAdd(&s_nzodd, cnt);
    __syncthreads();
    if (threadIdx.x == 0) {
        g_flags[0] = s_ok;
        g_flags[1] = (s_nzodd < 16) ? 1 : 0;
    }
}

__global__ void zero_nup_kernel() {
    int i = blockIdx.x * 256 + threadIdx.x;
    if (i < NXCD * NUP_STRIDE / 4) ((float4*)g_nup)[i] = make_float4(0.f, 0.f, 0.f, 0.f);
}

// one-time split-bf16 pack into the aligned staging layouts
__global__ void cvt_feat_kernel(const void* __restrict__ nraw,
                                const void* __restrict__ eraw) {
    const bool bf = (g_flags[0] != 0);
    const unsigned short* n16 = (const unsigned short*)nraw;
    const float*          n32 = (const float*)nraw;
    const unsigned short* e16 = (const unsigned short*)eraw;
    const float*          e32 = (const float*)eraw;
    int t = blockIdx.x * 256 + threadIdx.x;
    int S = gridDim.x * 256;
    for (int i = t; i < N_NODES * 40; i += S) {
        int n = i / 40, c = i - n * 40;
        unsigned wI = 0, wJ = 0;
        if (c < 39) wI = bf ? (unsigned)n16[n * 39 + c] : packsplit(n32[n * 39 + c]);
        if (c < 36) wJ = bf ? (unsigned)n16[n * 39 + 3 + c] : packsplit(n32[n * 39 + 3 + c]);
        g_nI[i] = wI;
        g_nJ[i] = wJ;
    }
    for (int i = t; i < N_EDGES * 12; i += S) {
        int e = i / 12, c = i - e * 12;
        int sc = (c < 8) ? (1 + c) : (c == 8) ? 0 : (c == 9) ? 9 : -1;
        unsigned w = 0;
        if (sc >= 0) {
            size_t k = (size_t)e * 10 + sc;
            w = bf ? (unsigned)e16[k] : packsplit(e32[k]);
        }
        g_eF[i] = w;
    }
}

__global__ void cvt_weights_kernel(const void* ew1, const void* eb1,
                                   const void* ew2, const void* eb2,
                                   const void* nw1, const void* nb1,
                                   const void* nw2, const void* nb2) {
    bool bf = (g_flags[0] != 0);
    int t = blockIdx.x * blockDim.x + threadIdx.x;
    int S = gridDim.x * blockDim.x;
    for (int i = t; i < 2816; i += S) g_W[EW1_O + i] = rd_any(ew1, i, bf);
    for (int i = t; i < 32;   i += S) g_W[EB1_O + i] = rd_any(eb1, i, bf);
    for (int i = t; i < 1024; i += S) g_W[EW2_O + i] = rd_any(ew2, i, bf);
    for (int i = t; i < 32;   i += S) g_W[EB2_O + i] = rd_any(eb2, i, bf);
    for (int i = t; i < 2272; i += S) g_W[NW1_O + i] = rd_any(nw1, i, bf);
    for (int i = t; i < 32;   i += S) g_W[NB1_O + i] = rd_any(nb1, i, bf);
    for (int i = t; i < 32;   i += S) g_W[NW2_O + i] = rd_any(nw2, i, bf);
    if (t == 0) g_W[NB2_O] = rd_any(nb2, 0, bf);
    for (int i = t; i < 96 * 32; i += S) {
        int r = i >> 5;
        float w = (r < 88) ? rd_any(ew1, i, bf) : 0.0f;  // pad rows ZERO (NaN guard)
        unsigned h = f2bf_u(w);
        unsigned l = f2bf_u(w - ubf2f(h));
        g_Wbf1[0][i] = (ushort_t)h;
        g_Wbf1[1][i] = (ushort_t)l;
    }
    for (int i = t; i < 1024; i += S) {
        float w = rd_any(ew2, i, bf);
        unsigned h = f2bf_u(w);
        unsigned l = f2bf_u(w - ubf2f(h));
        g_Wbf2[0][i] = (ushort_t)h;
        g_Wbf2[1][i] = (ushort_t)l;
    }
}

// ---------------------------------------------------------------------------
// MFMA edge kernel; staging = 5 gl16 + 2 gl4, ALL full-exec + 16B-aligned src.
// LDS slot map (words, per wave): op k base = 256k, lane l -> base + 4l.
//   op0: j(q)=q      src NS+4q       op1: j=4+q  src NS+16+4q
//   op2: j={8,10,11,13} src {NS+32, EF+0, EF+4, NJ+0}
//   op3: j=14+q src NJ+4+4q          op4: j=18+q src NJ+20+4q
//   opA(gl4) word 1280+4e+c: {NS36,NS37,NS38,EF0} of edge l>>2
//   opB(gl4) word 1344+4e+c: {EF9,ND0,ND1,ND2}    of edge l>>2
//   words 1408..1535: pre-zeroed (j=22,23 -> W1 zero rows)
// Iter schedule: vmcnt(8); SB; 6 ds_read_b128; lgkmcnt(0); SB; stage+idx; SB;
// MFMA/tanh/atomics.  vmcnt(8) leaves only the 8 newest (prev atomics) in
// flight => stage proven landed, atomic commit never on the critical path.
// ---------------------------------------------------------------------------
__launch_bounds__(256, 3)
__global__ void edge_kernel_mfma(const int* __restrict__ ei) {
    const int lane = threadIdx.x & 63;
    const int wv   = threadIdx.x >> 6;
    const int jc   = lane & 15;    // edge-in-tile / A-row / D-col
    const int gq   = lane >> 4;    // k-octet group / D-row block
    const bool i64 = (g_flags[1] != 0);

    // --- pinned B fragments: W1 (48 VGPR) + W2 (16 VGPR) ---
    union FR { int i[4]; bf16x8 v; };
    FR w1f[2][2][3], w2f[2][2];    // [plane][n-tile][k-step]
#pragma unroll
    for (int pl = 0; pl < 2; pl++)
#pragma unroll
        for (int t = 0; t < 2; t++)
#pragma unroll
            for (int kk = 0; kk < 3; kk++)
#pragma unroll
                for (int q = 0; q < 4; q++) {
                    int k0 = 32 * kk + 8 * gq + 2 * q;
                    int lo = g_Wbf1[pl][(k0 + 0) * 32 + 16 * t + jc];
                    int hi = g_Wbf1[pl][(k0 + 1) * 32 + 16 * t + jc];
                    w1f[pl][t][kk].i[q] = (lo & 0xffff) | (hi << 16);
                }
#pragma unroll
    for (int pl = 0; pl < 2; pl++)
#pragma unroll
        for (int t = 0; t < 2; t++)
#pragma unroll
            for (int q = 0; q < 4; q++) {
                int k0 = 8 * gq + 2 * q;
                int lo = g_Wbf2[pl][(k0 + 0) * 32 + 16 * t + jc];
                int hi = g_Wbf2[pl][(k0 + 1) * 32 + 16 * t + jc];
                w2f[pl][t].i[q] = (lo & 0xffff) | (hi << 16);
            }
#pragma unroll
    for (int pl = 0; pl < 2; pl++)
#pragma unroll
        for (int t = 0; t < 2; t++) {
#pragma unroll
            for (int kk = 0; kk < 3; kk++)
#pragma unroll
                for (int q = 0; q < 4; q++) asm volatile("" : "+v"(w1f[pl][t][kk].i[q]));
#pragma unroll
            for (int q = 0; q < 4; q++) asm volatile("" : "+v"(w2f[pl][t].i[q]));
        }
    float b1c[2], b2c[2];
#pragma unroll
    for (int t = 0; t < 2; t++) {
        b1c[t] = g_W[EB1_O + 16 * t + jc];
        b2c[t] = g_W[EB2_O + 16 * t + jc];
    }

    __shared__ __align__(16) unsigned Xst[4][1536];
    __shared__ __align__(16) ushort_t HsH[4][640], HsL[4][640];

    // pre-zero the j=22/23 region (never staged; multiplies W1 zero rows)
    *(uint2*)&Xst[wv][1408 + lane * 2] = make_uint2(0u, 0u);

    // per-lane fragment read word-offsets (compile-once cndmask chains)
    const int w00 = 128 * gq, w01 = 128 * gq + 64;
    const int w10 = (gq == 0) ? 512 : (gq == 1) ? 576 : (gq == 2) ? 1344 : 768;
    const int w11 = (gq == 0) ? 1280 : (gq == 1) ? 640 : (gq == 2) ? 704 : 832;
    const int w20 = (gq == 0) ? 896 : (gq == 1) ? 1024 : (gq == 2) ? 1152 : 1408;
    const int w21 = (gq == 0) ? 960 : (gq == 1) ? 1088 : (gq == 2) ? 1216 : 1472;

    unsigned xcc;
    asm volatile("s_getreg_b32 %0, hwreg(HW_REG_XCC_ID)" : "=s"(xcc));
    float* nup = g_nup + (xcc & 7) * NUP_STRIDE;

    const int stride = gridDim.x * 4;
    int tile = blockIdx.x * 4 + wv;
    if (tile >= E_TILES) return;

    auto ld_main = [&](int tt, int& s, int& d, int& a, int& b) {
        int es = tt * 16 + jc;          // this lane's tile edge
        int ea = tt * 16 + (lane >> 2); // mixed-op edge
        if (i64) {
            s = ei[2 * es]; d = ei[2 * (N_EDGES + es)];
            a = ei[2 * ea]; b = ei[2 * (N_EDGES + ea)];
        } else {
            s = ei[es]; d = ei[N_EDGES + es];
            a = ei[ea]; b = ei[N_EDGES + ea];
        }
    };
    auto ld_ra = [&](int tt, int* r) {
        int ea = tt * 16 + 4 * gq;
        if (i64) {
#pragma unroll
            for (int k = 0; k < 4; k++) r[k] = ei[2 * (ea + k)];
        } else {
            int4 v = *(const int4*)&ei[ea];
            r[0] = v.x; r[1] = v.y; r[2] = v.z; r[3] = v.w;
        }
    };
    auto stage = [&](int tt, int ssv, int sdv, int sav, int sbv) {
        int sv = ssv; if ((unsigned)sv >= N_NODES) sv = 0;
        int dv = sdv; if ((unsigned)dv >= N_NODES) dv = 0;
        int av = sav; if ((unsigned)av >= N_NODES) av = 0;
        int bv = sbv; if ((unsigned)bv >= N_NODES) bv = 0;
        const unsigned* NS = g_nI + (size_t)sv * 40;             // 160B rows: aligned
        const unsigned* NJ = g_nJ + (size_t)dv * 40;
        const unsigned* EF = g_eF + ((size_t)tt * 16 + jc) * 12; // 48B rows: aligned
        const unsigned* EA = g_eF + ((size_t)tt * 16 + (lane >> 2)) * 12;
        const unsigned* NA = g_nI + (size_t)av * 40;
        const unsigned* NB = g_nI + (size_t)bv * 40;
        unsigned* XB = &Xst[wv][0];
        const int q = gq, c = lane & 3;
        gl16(NS + 4 * q,      XB + 0);
        gl16(NS + 16 + 4 * q, XB + 256);
        const unsigned* p2 = (q == 0) ? NS + 32 : (q == 1) ? EF + 0
                           : (q == 2) ? EF + 4  : NJ + 0;
        gl16(p2,              XB + 512);
        gl16(NJ + 4 + 4 * q,  XB + 768);
        gl16(NJ + 20 + 4 * q, XB + 1024);
        const unsigned* pA = (c < 3) ? NA + 36 + c : EA + 8;   // {NS36..38, EF0}
        gl4(pA, XB + 1280);
        const unsigned* pB = (c == 0) ? EA + 9 : NB + (c - 1); // {EF9, ND0..2}
        gl4(pB, XB + 1344);
    };

    // prologue
    int ss_n, sd_n, sa_n, sb_n, ss_f, sd_f, sa_f, sb_f;
    int ra_c[4], ra_n[4];
    ld_main(tile, ss_n, sd_n, sa_n, sb_n);
    ld_ra(tile, ra_c);
    stage(tile, ss_n, sd_n, sa_n, sb_n);
    {
        int t1 = tile + stride;
        if (t1 < E_TILES) ld_main(t1, ss_n, sd_n, sa_n, sb_n);
    }
    asm volatile("s_waitcnt vmcnt(0)" ::: "memory");

    const unsigned* Xw = &Xst[wv][4 * jc];
    int t = tile;
    for (;;) {
        const int  tn  = t + stride;
        const int  tnn = tn + stride;
        const bool hn  = (tn < E_TILES);

        asm volatile("s_waitcnt vmcnt(8)" ::: "memory");
        __builtin_amdgcn_sched_barrier(0);

        // read this tile's 6 fragment quads into regs, COMPLETE before restage
        uint4 c00 = *(const uint4*)(Xw + w00);
        uint4 c01 = *(const uint4*)(Xw + w01);
        uint4 c10 = *(const uint4*)(Xw + w10);
        uint4 c11 = *(const uint4*)(Xw + w11);
        uint4 c20 = *(const uint4*)(Xw + w20);
        uint4 c21 = *(const uint4*)(Xw + w21);
        asm volatile("s_waitcnt lgkmcnt(0)" ::: "memory");
        __builtin_amdgcn_sched_barrier(0);

        if (hn) {
            stage(tn, ss_n, sd_n, sa_n, sb_n);
            ld_ra(tn, ra_n);
        }
        if (tnn < E_TILES) ld_main(tnn, ss_f, sd_f, sa_f, sb_f);
        __builtin_amdgcn_sched_barrier(0);

        // layer 1: build split fragments + 18 MFMA
        f32x4 acc[2];
#pragma unroll
        for (int tt = 0; tt < 2; tt++) acc[tt] = (f32x4){b1c[tt], b1c[tt], b1c[tt], b1c[tt]};
#pragma unroll
        for (int kk = 0; kk < 3; kk++) {
            uint4 c0 = (kk == 0) ? c00 : (kk == 1) ? c10 : c20;
            uint4 c1 = (kk == 0) ? c01 : (kk == 1) ? c11 : c21;
            FR ah, al;
            ah.i[0] = (c0.x & 0xffff) | (c0.y << 16);
            ah.i[1] = (c0.z & 0xffff) | (c0.w << 16);
            ah.i[2] = (c1.x & 0xffff) | (c1.y << 16);
            ah.i[3] = (c1.z & 0xffff) | (c1.w << 16);
            al.i[0] = (c0.x >> 16) | (c0.y & 0xffff0000u);
            al.i[1] = (c0.z >> 16) | (c0.w & 0xffff0000u);
            al.i[2] = (c1.x >> 16) | (c1.y & 0xffff0000u);
            al.i[3] = (c1.z >> 16) | (c1.w & 0xffff0000u);
#pragma unroll
            for (int tt = 0; tt < 2; tt++) {
                acc[tt] = __builtin_amdgcn_mfma_f32_16x16x32_bf16(ah.v, w1f[0][tt][kk].v, acc[tt], 0, 0, 0);
                acc[tt] = __builtin_amdgcn_mfma_f32_16x16x32_bf16(ah.v, w1f[1][tt][kk].v, acc[tt], 0, 0, 0);
                acc[tt] = __builtin_amdgcn_mfma_f32_16x16x32_bf16(al.v, w1f[0][tt][kk].v, acc[tt], 0, 0, 0);
            }
        }

        // h = tanh, split hi+lo -> LDS
#pragma unroll
        for (int tt = 0; tt < 2; tt++)
#pragma unroll
            for (int r = 0; r < 4; r++) {
                float h = fast_tanh(acc[tt][r]);
                unsigned hh = f2bf_u(h);
                unsigned hl = f2bf_u(h - ubf2f(hh));
                int idx = (4 * gq + r) * 40 + 16 * tt + jc;
                HsH[wv][idx] = (ushort_t)hh;
                HsL[wv][idx] = (ushort_t)hl;
            }

        // layer 2: 6 MFMA
        f32x4 a2[2];
#pragma unroll
        for (int tt = 0; tt < 2; tt++) a2[tt] = (f32x4){b2c[tt], b2c[tt], b2c[tt], b2c[tt]};
        {
            bf16x8 hh8 = *(const bf16x8*)&HsH[wv][jc * 40 + 8 * gq];
            bf16x8 hl8 = *(const bf16x8*)&HsL[wv][jc * 40 + 8 * gq];
#pragma unroll
            for (int tt = 0; tt < 2; tt++) {
                a2[tt] = __builtin_amdgcn_mfma_f32_16x16x32_bf16(hh8, w2f[0][tt].v, a2[tt], 0, 0, 0);
                a2[tt] = __builtin_amdgcn_mfma_f32_16x16x32_bf16(hh8, w2f[1][tt].v, a2[tt], 0, 0, 0);
                a2[tt] = __builtin_amdgcn_mfma_f32_16x16x32_bf16(hl8, w2f[0][tt].v, a2[tt], 0, 0, 0);
            }
        }

        // e_up = tanh -> XCD-local atomics (the 8 newest vmem ops at next wait)
#pragma unroll
        for (int r = 0; r < 4; r++) {
            int sv = ra_c[r]; if ((unsigned)sv >= N_NODES) sv = 0;
#pragma unroll
            for (int tt = 0; tt < 2; tt++)
                __hip_atomic_fetch_add(&nup[sv * 32 + 16 * tt + jc], fast_tanh(a2[tt][r]),
                                       __ATOMIC_RELAXED, __HIP_MEMORY_SCOPE_WORKGROUP);
        }

        if (!hn) break;
        t = tn;
        ss_n = ss_f; sd_n = sd_f; sa_n = sa_f; sb_n = sb_f;
#pragma unroll
        for (int k = 0; k < 4; k++) ra_c[k] = ra_n[k];
    }
}

// node MLP unchanged: sums the 8 XCD-private n_up copies during gather
__launch_bounds__(256, 2)
__global__ void node_kernel(const void* __restrict__ nraw,
                            float* __restrict__ out) {
    const int lane = threadIdx.x & 63;
    const int wv   = threadIdx.x >> 6;
    const int jcol = lane & 31;
    const int half = lane >> 5;
    const bool bf  = (g_flags[0] != 0);

    float w1c[72];
#pragma unroll
    for (int r = 0; r < 71; r++) w1c[r] = g_W[NW1_O + r * 32 + jcol];
    w1c[71] = 0.0f;
#pragma unroll
    for (int r = 0; r < 72; r++) asm volatile("" : "+v"(w1c[r]));
    const float w2e = g_W[NW2_O + jcol];
    const float b1  = g_W[NB1_O + jcol];
    const float b2  = g_W[NB2_O];

    __shared__ __align__(16) float sx[4][4][2][72];

    const unsigned short* n16 = (const unsigned short*)nraw;
    const float*          n32 = (const float*)nraw;

    int gw = blockIdx.x * 4 + wv;
    int stride = gridDim.x * 4;
    for (int g = gw; g < N_GROUPS; g += stride) {
        const int id0 = g * 8 + half * 4;
#pragma unroll
        for (int s = 0; s < 4; s++) {
            const int id = id0 + s;
#pragma unroll
            for (int it = 0; it < 3; it++) {
                int t = jcol + it * 32;
                if (t < 72) {
                    float v;
                    if (t < 32) {
                        const float* p = g_nup + id * 32 + t;
                        v = p[0];
#pragma unroll
                        for (int x = 1; x < NXCD; x++) v += p[x * NUP_STRIDE];
                    }
                    else if (t < 71) v = bf ? bf2f(n16[id * 39 + (t - 32)])
                                            : n32[id * 39 + (t - 32)];
                    else             v = 0.0f;
                    sx[wv][s][half][t] = v;
                }
            }
        }
        float acc0 = b1, acc1 = b1, acc2 = b1, acc3 = b1;
#pragma unroll
        for (int q = 0; q < 18; q++) {
            float4 x0 = ((const float4*)sx[wv][0][half])[q];
            float4 x1 = ((const float4*)sx[wv][1][half])[q];
            float4 x2 = ((const float4*)sx[wv][2][half])[q];
            float4 x3 = ((const float4*)sx[wv][3][half])[q];
            acc0 = fmaf(x0.x, w1c[4*q+0], acc0); acc0 = fmaf(x0.y, w1c[4*q+1], acc0);
            acc0 = fmaf(x0.z, w1c[4*q+2], acc0); acc0 = fmaf(x0.w, w1c[4*q+3], acc0);
            acc1 = fmaf(x1.x, w1c[4*q+0], acc1); acc1 = fmaf(x1.y, w1c[4*q+1], acc1);
            acc1 = fmaf(x1.z, w1c[4*q+2], acc1); acc1 = fmaf(x1.w, w1c[4*q+3], acc1);
            acc2 = fmaf(x2.x, w1c[4*q+0], acc2); acc2 = fmaf(x2.y, w1c[4*q+1], acc2);
            acc2 = fmaf(x2.z, w1c[4*q+2], acc2); acc2 = fmaf(x2.w, w1c[4*q+3], acc2);
            acc3 = fmaf(x3.x, w1c[4*q+0], acc3); acc3 = fmaf(x3.y, w1c[4*q+1], acc3);
            acc3 = fmaf(x3.z, w1c[4*q+2], acc3); acc3 = fmaf(x3.w, w1c[4*q+3], acc3);
        }
        float t0 = fast_tanh(acc0) * w2e;
        float t1 = fast_tanh(acc1) * w2e;
        float t2 = fast_tanh(acc2) * w2e;
        float t3 = fast_tanh(acc3) * w2e;
#pragma unroll
        for (int m = 1; m < 32; m <<= 1) {
            t0 += __shfl_xor(t0, m, 64);
            t1 += __shfl_xor(t1, m, 64);
            t2 += __shfl_xor(t2, m, 64);
            t3 += __shfl_xor(t3, m, 64);
        }
        if (jcol == 0) {
            out[id0 + 0] = t0 + b2;
            out[id0 + 1] = t1 + b2;
            out[id0 + 2] = t2 + b2;
            out[id0 + 3] = t3 + b2;
        }
    }
}

extern "C" void kernel_launch(void* const* d_in, const int* in_sizes, int n_in,
                              void* d_out, int out_size, void* d_ws, size_t ws_size,
                              hipStream_t stream) {
    const void* n_raw = d_in[0];
    const void* e_raw = d_in[1];
    const int*  ei    = (const int*)d_in[2];

    detect_kernel<<<1, 256, 0, stream>>>((const unsigned short*)d_in[4], ei);
    zero_nup_kernel<<<(NXCD * NUP_STRIDE / 4 + 255) / 256, 256, 0, stream>>>();
    cvt_weights_kernel<<<16, 256, 0, stream>>>(d_in[4], d_in[5], d_in[6], d_in[7],
                                               d_in[8], d_in[9], d_in[10], d_in[11]);
    cvt_feat_kernel<<<4096, 256, 0, stream>>>(n_raw, e_raw);
    edge_kernel_mfma<<<2048, 256, 0, stream>>>(ei);
    node_kernel<<<512, 256, 0, stream>>>(n_raw, (float*)d_out);
}

// Round 7
// 728.167 us; speedup vs baseline: 1.4138x; 1.4138x over previous
//
#include <hip/hip_runtime.h>
#include <hip/hip_bf16.h>

#define N_NODES 100000
#define N_EDGES 3200000
#define E_TILES  (N_EDGES / 16)  // 16 edges per wave-iteration
#define N_GROUPS (N_NODES / 8)
#define NXCD 8
#define NUPW (N_NODES * 16)      // u32 words (f16 pairs) per XCD-private copy

// weight sub-offsets in g_W (fp32 copies)
#define EW1_O 0
#define EB1_O 2816
#define EW2_O 2848
#define EB2_O 3872
#define NW1_O 3904
#define NB1_O 6176
#define NW2_O 6208
#define NB2_O 6240

typedef unsigned short ushort_t;
typedef __attribute__((ext_vector_type(8))) short bf16x8;
typedef __attribute__((ext_vector_type(4))) float f32x4;

// Device-global state, rebuilt from inputs on EVERY call.
// g_nupP: 8 XCD-private accumulators of PACKED f16 pairs (word c holds
// components 2c,2c+1 of a node's 32-dim n_up). Committed with
// global_atomic_pk_add_f16 (XCD-L2-local RMW): halves TCC atomic op count vs
// fp32 dwords -- r6 showed that op rate (152G/s, saturated across 3 kernel
// structures) is the wall. f16 accumulation error ~4e-3 on n_up, ~1e-3..5e-3
// on output; threshold 3.48e-2.
__device__ unsigned g_nupP[NXCD * NUPW];
__device__ float    g_W[6244];                 // fp32 weights
__device__ ushort_t g_Wbf1[2][96 * 32];        // W1 split planes (hi,lo), K 88->96 pad
__device__ ushort_t g_Wbf2[2][32 * 32];        // W2 split planes (hi,lo)
// packed split-bf16 feature tables; word = hi | (lo<<16).  ALL gl16 sources must
// be 16B-aligned (round-5 NaN root cause) -> padded/shifted layouts:
__device__ unsigned g_nI[N_NODES * 40];        // node feats, rows padded 39->40
__device__ unsigned g_nJ[N_NODES * 40];        // node feats shifted by 3 (dst window)
__device__ unsigned g_eF[N_EDGES * 12];        // edge feats {EF1..8, EF0, EF9, 0,0}
__device__ int      g_flags[2];                // [0]: bf16 inputs; [1]: int64 idx

__device__ __forceinline__ float bf2f(unsigned short u) {
    union { unsigned int i; float f; } c; c.i = ((unsigned int)u) << 16; return c.f;
}
__device__ __forceinline__ float ubf2f(unsigned u) {
    union { unsigned int i; float f; } c; c.i = u << 16; return c.f;
}
__device__ __forceinline__ unsigned f2bf_u(float f) {
    union { float f; unsigned u; } c; c.f = f;
    return (c.u + 0x7fffu + ((c.u >> 16) & 1u)) >> 16;
}
__device__ __forceinline__ unsigned packsplit(float x) {
    unsigned h = f2bf_u(x);
    unsigned l = f2bf_u(x - ubf2f(h));
    return (h & 0xffffu) | (l << 16);
}
__device__ __forceinline__ float rd_any(const void* p, int i, bool bf) {
    if (bf) return bf2f(((const unsigned short*)p)[i]);
    return ((const float*)p)[i];
}
__device__ __forceinline__ float fast_tanh(float x) {
    float ax = fabsf(x);
    float e  = __expf(ax * 2.0f);
    float t  = 1.0f - 2.0f / (e + 1.0f);
    return copysignf(t, x);
}
__device__ __forceinline__ float h16f(unsigned short b) {
    union { ushort_t s; _Float16 h; } c; c.s = b; return (float)c.h;
}

// async global->LDS, FULL-EXEC only (uniform LDS base, per-lane global src,
// lane l writes at base + l*size). 16B src alignment required.
__device__ __forceinline__ void gl16(const unsigned* g, unsigned* l) {
    __builtin_amdgcn_global_load_lds((const __attribute__((address_space(1))) void*)g,
                                     (__attribute__((address_space(3))) void*)l, 16, 0, 0);
}
__device__ __forceinline__ void gl4(const unsigned* g, unsigned* l) {
    __builtin_amdgcn_global_load_lds((const __attribute__((address_space(1))) void*)g,
                                     (__attribute__((address_space(3))) void*)l, 4, 0, 0);
}

__global__ void detect_kernel(const unsigned short* __restrict__ ew1_raw,
                              const int* __restrict__ ei32) {
    __shared__ int s_ok, s_nzodd;
    if (threadIdx.x == 0) { s_ok = 1; s_nzodd = 0; }
    __syncthreads();
    bool ok = true;
    for (int i = threadIdx.x; i < 2816; i += 256) {
        float v = bf2f(ew1_raw[i]);
        if (!(fabsf(v) <= 0.25f)) ok = false;
    }
    if (!ok) atomicAnd(&s_ok, 0);
    int cnt = 0;
    for (int i = threadIdx.x; i < 2048; i += 256)
        if (ei32[2 * i + 1] != 0) cnt++;
    if (cnt) atomicAdd(&s_nzodd, cnt);
    __syncthreads();
    if (threadIdx.x == 0) {
        g_flags[0] = s_ok;
        g_flags[1] = (s_nzodd < 16) ? 1 : 0;
    }
}

__global__ void zero_nup_kernel() {
    int i = blockIdx.x * 256 + threadIdx.x;
    if (i < NXCD * NUPW / 4) ((uint4*)g_nupP)[i] = make_uint4(0u, 0u, 0u, 0u);
}

// one-time split-bf16 pack into the aligned staging layouts
__global__ void cvt_feat_kernel(const void* __restrict__ nraw,
                                const void* __restrict__ eraw) {
    const bool bf = (g_flags[0] != 0);
    const unsigned short* n16 = (const unsigned short*)nraw;
    const float*          n32 = (const float*)nraw;
    const unsigned short* e16 = (const unsigned short*)eraw;
    const float*          e32 = (const float*)eraw;
    int t = blockIdx.x * 256 + threadIdx.x;
    int S = gridDim.x * 256;
    for (int i = t; i < N_NODES * 40; i += S) {
        int n = i / 40, c = i - n * 40;
        unsigned wI = 0, wJ = 0;
        if (c < 39) wI = bf ? (unsigned)n16[n * 39 + c] : packsplit(n32[n * 39 + c]);
        if (c < 36) wJ = bf ? (unsigned)n16[n * 39 + 3 + c] : packsplit(n32[n * 39 + 3 + c]);
        g_nI[i] = wI;
        g_nJ[i] = wJ;
    }
    for (int i = t; i < N_EDGES * 12; i += S) {
        int e = i / 12, c = i - e * 12;
        int sc = (c < 8) ? (1 + c) : (c == 8) ? 0 : (c == 9) ? 9 : -1;
        unsigned w = 0;
        if (sc >= 0) {
            size_t k = (size_t)e * 10 + sc;
            w = bf ? (unsigned)e16[k] : packsplit(e32[k]);
        }
        g_eF[i] = w;
    }
}

__global__ void cvt_weights_kernel(const void* ew1, const void* eb1,
                                   const void* ew2, const void* eb2,
                                   const void* nw1, const void* nb1,
                                   const void* nw2, const void* nb2) {
    bool bf = (g_flags[0] != 0);
    int t = blockIdx.x * blockDim.x + threadIdx.x;
    int S = gridDim.x * blockDim.x;
    for (int i = t; i < 2816; i += S) g_W[EW1_O + i] = rd_any(ew1, i, bf);
    for (int i = t; i < 32;   i += S) g_W[EB1_O + i] = rd_any(eb1, i, bf);
    for (int i = t; i < 1024; i += S) g_W[EW2_O + i] = rd_any(ew2, i, bf);
    for (int i = t; i < 32;   i += S) g_W[EB2_O + i] = rd_any(eb2, i, bf);
    for (int i = t; i < 2272; i += S) g_W[NW1_O + i] = rd_any(nw1, i, bf);
    for (int i = t; i < 32;   i += S) g_W[NB1_O + i] = rd_any(nb1, i, bf);
    for (int i = t; i < 32;   i += S) g_W[NW2_O + i] = rd_any(nw2, i, bf);
    if (t == 0) g_W[NB2_O] = rd_any(nb2, 0, bf);
    for (int i = t; i < 96 * 32; i += S) {
        int r = i >> 5;
        float w = (r < 88) ? rd_any(ew1, i, bf) : 0.0f;  // pad rows ZERO (NaN guard)
        unsigned h = f2bf_u(w);
        unsigned l = f2bf_u(w - ubf2f(h));
        g_Wbf1[0][i] = (ushort_t)h;
        g_Wbf1[1][i] = (ushort_t)l;
    }
    for (int i = t; i < 1024; i += S) {
        float w = rd_any(ew2, i, bf);
        unsigned h = f2bf_u(w);
        unsigned l = f2bf_u(w - ubf2f(h));
        g_Wbf2[0][i] = (ushort_t)h;
        g_Wbf2[1][i] = (ushort_t)l;
    }
}

// ---------------------------------------------------------------------------
// MFMA edge kernel; staging = 5 gl16 + 2 gl4, full-exec + 16B-aligned src
// (unchanged from r6). Commit: 4 global_atomic_pk_add_f16 per lane-iter
// (was 8 fp32 atomics) into the XCD-private packed accumulator.
// Iter: vmcnt(4); SB; 6 ds_read_b128; lgkmcnt(0); SB; stage+idx; SB;
// MFMA/tanh/shuffle-pack/atomics. vmcnt(4) leaves only the 4 newest (prev
// pk-atomics) in flight => stage proven landed, atomics never drained on
// the critical path.
// ---------------------------------------------------------------------------
__launch_bounds__(256, 3)
__global__ void edge_kernel_mfma(const int* __restrict__ ei) {
    const int lane = threadIdx.x & 63;
    const int wv   = threadIdx.x >> 6;
    const int jc   = lane & 15;    // edge-in-tile / A-row / D-col
    const int gq   = lane >> 4;    // k-octet group / D-row block
    const bool i64 = (g_flags[1] != 0);

    // --- pinned B fragments: W1 (48 VGPR) + W2 (16 VGPR) ---
    union FR { int i[4]; bf16x8 v; };
    FR w1f[2][2][3], w2f[2][2];    // [plane][n-tile][k-step]
#pragma unroll
    for (int pl = 0; pl < 2; pl++)
#pragma unroll
        for (int t = 0; t < 2; t++)
#pragma unroll
            for (int kk = 0; kk < 3; kk++)
#pragma unroll
                for (int q = 0; q < 4; q++) {
                    int k0 = 32 * kk + 8 * gq + 2 * q;
                    int lo = g_Wbf1[pl][(k0 + 0) * 32 + 16 * t + jc];
                    int hi = g_Wbf1[pl][(k0 + 1) * 32 + 16 * t + jc];
                    w1f[pl][t][kk].i[q] = (lo & 0xffff) | (hi << 16);
                }
#pragma unroll
    for (int pl = 0; pl < 2; pl++)
#pragma unroll
        for (int t = 0; t < 2; t++)
#pragma unroll
            for (int q = 0; q < 4; q++) {
                int k0 = 8 * gq + 2 * q;
                int lo = g_Wbf2[pl][(k0 + 0) * 32 + 16 * t + jc];
                int hi = g_Wbf2[pl][(k0 + 1) * 32 + 16 * t + jc];
                w2f[pl][t].i[q] = (lo & 0xffff) | (hi << 16);
            }
#pragma unroll
    for (int pl = 0; pl < 2; pl++)
#pragma unroll
        for (int t = 0; t < 2; t++) {
#pragma unroll
            for (int kk = 0; kk < 3; kk++)
#pragma unroll
                for (int q = 0; q < 4; q++) asm volatile("" : "+v"(w1f[pl][t][kk].i[q]));
#pragma unroll
            for (int q = 0; q < 4; q++) asm volatile("" : "+v"(w2f[pl][t].i[q]));
        }
    float b1c[2], b2c[2];
#pragma unroll
    for (int t = 0; t < 2; t++) {
        b1c[t] = g_W[EB1_O + 16 * t + jc];
        b2c[t] = g_W[EB2_O + 16 * t + jc];
    }

    __shared__ __align__(16) unsigned Xst[4][1536];
    __shared__ __align__(16) ushort_t HsH[4][640], HsL[4][640];

    // pre-zero the j=22/23 region (never staged; multiplies W1 zero rows)
    *(uint2*)&Xst[wv][1408 + lane * 2] = make_uint2(0u, 0u);

    // per-lane fragment read word-offsets
    const int w00 = 128 * gq, w01 = 128 * gq + 64;
    const int w10 = (gq == 0) ? 512 : (gq == 1) ? 576 : (gq == 2) ? 1344 : 768;
    const int w11 = (gq == 0) ? 1280 : (gq == 1) ? 640 : (gq == 2) ? 704 : 832;
    const int w20 = (gq == 0) ? 896 : (gq == 1) ? 1024 : (gq == 2) ? 1152 : 1408;
    const int w21 = (gq == 0) ? 960 : (gq == 1) ? 1088 : (gq == 2) ? 1216 : 1472;

    unsigned xcc;
    asm volatile("s_getreg_b32 %0, hwreg(HW_REG_XCC_ID)" : "=s"(xcc));
    unsigned* nupP = g_nupP + (size_t)(xcc & 7) * NUPW;

    const int stride = gridDim.x * 4;
    int tile = blockIdx.x * 4 + wv;
    if (tile >= E_TILES) return;

    auto ld_main = [&](int tt, int& s, int& d, int& a, int& b) {
        int es = tt * 16 + jc;
        int ea = tt * 16 + (lane >> 2);
        if (i64) {
            s = ei[2 * es]; d = ei[2 * (N_EDGES + es)];
            a = ei[2 * ea]; b = ei[2 * (N_EDGES + ea)];
        } else {
            s = ei[es]; d = ei[N_EDGES + es];
            a = ei[ea]; b = ei[N_EDGES + ea];
        }
    };
    auto ld_ra = [&](int tt, int* r) {
        int ea = tt * 16 + 4 * gq;
        if (i64) {
#pragma unroll
            for (int k = 0; k < 4; k++) r[k] = ei[2 * (ea + k)];
        } else {
            int4 v = *(const int4*)&ei[ea];
            r[0] = v.x; r[1] = v.y; r[2] = v.z; r[3] = v.w;
        }
    };
    auto stage = [&](int tt, int ssv, int sdv, int sav, int sbv) {
        int sv = ssv; if ((unsigned)sv >= N_NODES) sv = 0;
        int dv = sdv; if ((unsigned)dv >= N_NODES) dv = 0;
        int av = sav; if ((unsigned)av >= N_NODES) av = 0;
        int bv = sbv; if ((unsigned)bv >= N_NODES) bv = 0;
        const unsigned* NS = g_nI + (size_t)sv * 40;
        const unsigned* NJ = g_nJ + (size_t)dv * 40;
        const unsigned* EF = g_eF + ((size_t)tt * 16 + jc) * 12;
        const unsigned* EA = g_eF + ((size_t)tt * 16 + (lane >> 2)) * 12;
        const unsigned* NA = g_nI + (size_t)av * 40;
        const unsigned* NB = g_nI + (size_t)bv * 40;
        unsigned* XB = &Xst[wv][0];
        const int q = gq, c = lane & 3;
        gl16(NS + 4 * q,      XB + 0);
        gl16(NS + 16 + 4 * q, XB + 256);
        const unsigned* p2 = (q == 0) ? NS + 32 : (q == 1) ? EF + 0
                           : (q == 2) ? EF + 4  : NJ + 0;
        gl16(p2,              XB + 512);
        gl16(NJ + 4 + 4 * q,  XB + 768);
        gl16(NJ + 20 + 4 * q, XB + 1024);
        const unsigned* pA = (c < 3) ? NA + 36 + c : EA + 8;   // {NS36..38, EF0}
        gl4(pA, XB + 1280);
        const unsigned* pB = (c == 0) ? EA + 9 : NB + (c - 1); // {EF9, ND0..2}
        gl4(pB, XB + 1344);
    };

    // prologue
    int ss_n, sd_n, sa_n, sb_n, ss_f, sd_f, sa_f, sb_f;
    int ra_c[4], ra_n[4];
    ld_main(tile, ss_n, sd_n, sa_n, sb_n);
    ld_ra(tile, ra_c);
    stage(tile, ss_n, sd_n, sa_n, sb_n);
    {
        int t1 = tile + stride;
        if (t1 < E_TILES) ld_main(t1, ss_n, sd_n, sa_n, sb_n);
    }
    asm volatile("s_waitcnt vmcnt(0)" ::: "memory");

    const unsigned* Xw = &Xst[wv][4 * jc];
    const int sl = 16 * gq + ((2 * jc) & 15);   // shuffle source lane (component regroup)
    int t = tile;
    for (;;) {
        const int  tn  = t + stride;
        const int  tnn = tn + stride;
        const bool hn  = (tn < E_TILES);

        asm volatile("s_waitcnt vmcnt(4)" ::: "memory");
        __builtin_amdgcn_sched_barrier(0);

        // read this tile's 6 fragment quads into regs, COMPLETE before restage
        uint4 c00 = *(const uint4*)(Xw + w00);
        uint4 c01 = *(const uint4*)(Xw + w01);
        uint4 c10 = *(const uint4*)(Xw + w10);
        uint4 c11 = *(const uint4*)(Xw + w11);
        uint4 c20 = *(const uint4*)(Xw + w20);
        uint4 c21 = *(const uint4*)(Xw + w21);
        asm volatile("s_waitcnt lgkmcnt(0)" ::: "memory");
        __builtin_amdgcn_sched_barrier(0);

        if (hn) {
            stage(tn, ss_n, sd_n, sa_n, sb_n);
            ld_ra(tn, ra_n);
        }
        if (tnn < E_TILES) ld_main(tnn, ss_f, sd_f, sa_f, sb_f);
        __builtin_amdgcn_sched_barrier(0);

        // layer 1: build split fragments + 18 MFMA
        f32x4 acc[2];
#pragma unroll
        for (int tt = 0; tt < 2; tt++) acc[tt] = (f32x4){b1c[tt], b1c[tt], b1c[tt], b1c[tt]};
#pragma unroll
        for (int kk = 0; kk < 3; kk++) {
            uint4 c0 = (kk == 0) ? c00 : (kk == 1) ? c10 : c20;
            uint4 c1 = (kk == 0) ? c01 : (kk == 1) ? c11 : c21;
            FR ah, al;
            ah.i[0] = (c0.x & 0xffff) | (c0.y << 16);
            ah.i[1] = (c0.z & 0xffff) | (c0.w << 16);
            ah.i[2] = (c1.x & 0xffff) | (c1.y << 16);
            ah.i[3] = (c1.z & 0xffff) | (c1.w << 16);
            al.i[0] = (c0.x >> 16) | (c0.y & 0xffff0000u);
            al.i[1] = (c0.z >> 16) | (c0.w & 0xffff0000u);
            al.i[2] = (c1.x >> 16) | (c1.y & 0xffff0000u);
            al.i[3] = (c1.z >> 16) | (c1.w & 0xffff0000u);
#pragma unroll
            for (int tt = 0; tt < 2; tt++) {
                acc[tt] = __builtin_amdgcn_mfma_f32_16x16x32_bf16(ah.v, w1f[0][tt][kk].v, acc[tt], 0, 0, 0);
                acc[tt] = __builtin_amdgcn_mfma_f32_16x16x32_bf16(ah.v, w1f[1][tt][kk].v, acc[tt], 0, 0, 0);
                acc[tt] = __builtin_amdgcn_mfma_f32_16x16x32_bf16(al.v, w1f[0][tt][kk].v, acc[tt], 0, 0, 0);
            }
        }

        // h = tanh, split hi+lo -> LDS
#pragma unroll
        for (int tt = 0; tt < 2; tt++)
#pragma unroll
            for (int r = 0; r < 4; r++) {
                float h = fast_tanh(acc[tt][r]);
                unsigned hh = f2bf_u(h);
                unsigned hl = f2bf_u(h - ubf2f(hh));
                int idx = (4 * gq + r) * 40 + 16 * tt + jc;
                HsH[wv][idx] = (ushort_t)hh;
                HsL[wv][idx] = (ushort_t)hl;
            }

        // layer 2: 6 MFMA
        f32x4 a2[2];
#pragma unroll
        for (int tt = 0; tt < 2; tt++) a2[tt] = (f32x4){b2c[tt], b2c[tt], b2c[tt], b2c[tt]};
        {
            bf16x8 hh8 = *(const bf16x8*)&HsH[wv][jc * 40 + 8 * gq];
            bf16x8 hl8 = *(const bf16x8*)&HsL[wv][jc * 40 + 8 * gq];
#pragma unroll
            for (int tt = 0; tt < 2; tt++) {
                a2[tt] = __builtin_amdgcn_mfma_f32_16x16x32_bf16(hh8, w2f[0][tt].v, a2[tt], 0, 0, 0);
                a2[tt] = __builtin_amdgcn_mfma_f32_16x16x32_bf16(hh8, w2f[1][tt].v, a2[tt], 0, 0, 0);
                a2[tt] = __builtin_amdgcn_mfma_f32_16x16x32_bf16(hl8, w2f[0][tt].v, a2[tt], 0, 0, 0);
            }
        }

        // messages, regrouped so lane (gq,jc) holds components {2jc,2jc+1}:
        // all-lane shuffles (no divergence), then pack f16x2, 4 pk-atomics.
#pragma unroll
        for (int r = 0; r < 4; r++) {
            float m0 = fast_tanh(a2[0][r]);
            float m1 = fast_tanh(a2[1][r]);
            float loA = __shfl(m0, sl, 64),     hiA = __shfl(m0, sl + 1, 64);
            float loB = __shfl(m1, sl, 64),     hiB = __shfl(m1, sl + 1, 64);
            float lo  = (jc < 8) ? loA : loB;
            float hi  = (jc < 8) ? hiA : hiB;
            unsigned pk;
            asm("v_cvt_pkrtz_f16_f32 %0, %1, %2" : "=v"(pk) : "v"(lo), "v"(hi));
            int sv = ra_c[r]; if ((unsigned)sv >= N_NODES) sv = 0;
            unsigned* p = nupP + (size_t)sv * 16 + jc;
            asm volatile("global_atomic_pk_add_f16 %0, %1, off"
                         :: "v"(p), "v"(pk) : "memory");
        }

        if (!hn) break;
        t = tn;
        ss_n = ss_f; sd_n = sd_f; sa_n = sa_f; sb_n = sb_f;
#pragma unroll
        for (int k = 0; k < 4; k++) ra_c[k] = ra_n[k];
    }
}

// node MLP: sums the 8 XCD-private packed-f16 n_up copies during gather
__launch_bounds__(256, 2)
__global__ void node_kernel(const void* __restrict__ nraw,
                            float* __restrict__ out) {
    const int lane = threadIdx.x & 63;
    const int wv   = threadIdx.x >> 6;
    const int jcol = lane & 31;
    const int half = lane >> 5;
    const bool bf  = (g_flags[0] != 0);

    float w1c[72];
#pragma unroll
    for (int r = 0; r < 71; r++) w1c[r] = g_W[NW1_O + r * 32 + jcol];
    w1c[71] = 0.0f;
#pragma unroll
    for (int r = 0; r < 72; r++) asm volatile("" : "+v"(w1c[r]));
    const float w2e = g_W[NW2_O + jcol];
    const float b1  = g_W[NB1_O + jcol];
    const float b2  = g_W[NB2_O];

    __shared__ __align__(16) float sx[4][4][2][72];

    const unsigned short* n16 = (const unsigned short*)nraw;
    const float*          n32 = (const float*)nraw;

    int gw = blockIdx.x * 4 + wv;
    int stride = gridDim.x * 4;
    for (int g = gw; g < N_GROUPS; g += stride) {
        const int id0 = g * 8 + half * 4;
#pragma unroll
        for (int s = 0; s < 4; s++) {
            const int id = id0 + s;
#pragma unroll
            for (int it = 0; it < 3; it++) {
                int t = jcol + it * 32;
                if (t < 72) {
                    float v;
                    if (t < 32) {
                        const unsigned* p = g_nupP + (size_t)id * 16 + (t >> 1);
                        v = 0.0f;
#pragma unroll
                        for (int x = 0; x < NXCD; x++) {
                            unsigned u = p[(size_t)x * NUPW];
                            v += h16f((t & 1) ? (ushort_t)(u >> 16)
                                              : (ushort_t)(u & 0xffffu));
                        }
                    }
                    else if (t < 71) v = bf ? bf2f(n16[id * 39 + (t - 32)])
                                            : n32[id * 39 + (t - 32)];
                    else             v = 0.0f;
                    sx[wv][s][half][t] = v;
                }
            }
        }
        float acc0 = b1, acc1 = b1, acc2 = b1, acc3 = b1;
#pragma unroll
        for (int q = 0; q < 18; q++) {
            float4 x0 = ((const float4*)sx[wv][0][half])[q];
            float4 x1 = ((const float4*)sx[wv][1][half])[q];
            float4 x2 = ((const float4*)sx[wv][2][half])[q];
            float4 x3 = ((const float4*)sx[wv][3][half])[q];
            acc0 = fmaf(x0.x, w1c[4*q+0], acc0); acc0 = fmaf(x0.y, w1c[4*q+1], acc0);
            acc0 = fmaf(x0.z, w1c[4*q+2], acc0); acc0 = fmaf(x0.w, w1c[4*q+3], acc0);
            acc1 = fmaf(x1.x, w1c[4*q+0], acc1); acc1 = fmaf(x1.y, w1c[4*q+1], acc1);
            acc1 = fmaf(x1.z, w1c[4*q+2], acc1); acc1 = fmaf(x1.w, w1c[4*q+3], acc1);
            acc2 = fmaf(x2.x, w1c[4*q+0], acc2); acc2 = fmaf(x2.y, w1c[4*q+1], acc2);
            acc2 = fmaf(x2.z, w1c[4*q+2], acc2); acc2 = fmaf(x2.w, w1c[4*q+3], acc2);
            acc3 = fmaf(x3.x, w1c[4*q+0], acc3); acc3 = fmaf(x3.y, w1c[4*q+1], acc3);
            acc3 = fmaf(x3.z, w1c[4*q+2], acc3); acc3 = fmaf(x3.w, w1c[4*q+3], acc3);
        }
        float t0 = fast_tanh(acc0) * w2e;
        float t1 = fast_tanh(acc1) * w2e;
        float t2 = fast_tanh(acc2) * w2e;
        float t3 = fast_tanh(acc3) * w2e;
#pragma unroll
        for (int m = 1; m < 32; m <<= 1) {
            t0 += __shfl_xor(t0, m, 64);
            t1 += __shfl_xor(t1, m, 64);
            t2 += __shfl_xor(t2, m, 64);
            t3 += __shfl_xor(t3, m, 64);
        }
        if (jcol == 0) {
            out[id0 + 0] = t0 + b2;
            out[id0 + 1] = t1 + b2;
            out[id0 + 2] = t2 + b2;
            out[id0 + 3] = t3 + b2;
        }
    }
}

extern "C" void kernel_launch(void* const* d_in, const int* in_sizes, int n_in,
                              void* d_out, int out_size, void* d_ws, size_t ws_size,
                              hipStream_t stream) {
    const void* n_raw = d_in[0];
    const void* e_raw = d_in[1];
    const int*  ei    = (const int*)d_in[2];

    detect_kernel<<<1, 256, 0, stream>>>((const unsigned short*)d_in[4], ei);
    zero_nup_kernel<<<(NXCD * NUPW / 4 + 255) / 256, 256, 0, stream>>>();
    cvt_weights_kernel<<<16, 256, 0, stream>>>(d_in[4], d_in[5], d_in[6], d_in[7],
                                               d_in[8], d_in[9], d_in[10], d_in[11]);
    cvt_feat_kernel<<<4096, 256, 0, stream>>>(n_raw, e_raw);
    edge_kernel_mfma<<<2048, 256, 0, stream>>>(ei);
    node_kernel<<<512, 256, 0, stream>>>(n_raw, (float*)d_out);
}